// Round 15
// baseline (282.749 us; speedup 1.0000x reference)
//
#include <hip/hip_runtime.h>
#include <hip/hip_bf16.h>

typedef __attribute__((ext_vector_type(8))) __bf16 bf16x8;
typedef __attribute__((ext_vector_type(4))) float f32x4;

#define BATCH 16
#define LSEQ 2048
#define DIM 128
#define EPITCH 2056
#define NKBLK 64   // 2048 / 32

__device__ __forceinline__ bf16x8 cvt8(float4 a, float4 b) {
    bf16x8 r;
    r[0] = (__bf16)a.x; r[1] = (__bf16)a.y; r[2] = (__bf16)a.z; r[3] = (__bf16)a.w;
    r[4] = (__bf16)b.x; r[5] = (__bf16)b.y; r[6] = (__bf16)b.z; r[7] = (__bf16)b.w;
    return r;
}

// ============ preproc: K -> fragment-blocked Kf[b][kblk][j][lane] ============
__global__ __launch_bounds__(256)
void pack_k_kernel(const float* __restrict__ kg, bf16x8* __restrict__ kf) {
    __shared__ __bf16 Ks[32][DIM + 8];
    const int kblk = blockIdx.x, b = blockIdx.y;
    const int tid = threadIdx.x;
    {
        const int r = tid >> 3, c4 = tid & 7;
        const float* src = kg + ((size_t)b * LSEQ + kblk * 32 + r) * DIM;
        #pragma unroll
        for (int jj = 0; jj < 4; ++jj) {
            const int c = (c4 + 8 * jj) * 4;
            float4 x = *reinterpret_cast<const float4*>(src + c);
            Ks[r][c + 0] = (__bf16)x.x; Ks[r][c + 1] = (__bf16)x.y;
            Ks[r][c + 2] = (__bf16)x.z; Ks[r][c + 3] = (__bf16)x.w;
        }
    }
    __syncthreads();
    const int lane = tid & 63, w = tid >> 6;
    const int g = lane >> 4, li = lane & 15;
    bf16x8* dst = kf + ((size_t)b * NKBLK + kblk) * 8 * 64;
    #pragma unroll
    for (int jj = 0; jj < 2; ++jj) {
        const int j = 2 * w + jj;
        const int t = j >> 2, d = j & 3;
        bf16x8 v;
        #pragma unroll
        for (int e = 0; e < 8; ++e) v[e] = Ks[t * 16 + li][d * 32 + g * 8 + e];
        dst[j * 64 + lane] = v;
    }
}

// ============ preproc: V -> fragment-blocked Vf[b][kblk][dt][lane] ============
__global__ __launch_bounds__(256)
void pack_v_kernel(const float* __restrict__ vg, bf16x8* __restrict__ vf) {
    __shared__ __bf16 Vs[32][DIM + 8];
    const int kblk = blockIdx.x, b = blockIdx.y;
    const int tid = threadIdx.x;
    {
        const int r = tid >> 3, c4 = tid & 7;
        const float* src = vg + ((size_t)b * LSEQ + kblk * 32 + r) * DIM;
        #pragma unroll
        for (int jj = 0; jj < 4; ++jj) {
            const int c = (c4 + 8 * jj) * 4;
            float4 x = *reinterpret_cast<const float4*>(src + c);
            Vs[r][c + 0] = (__bf16)x.x; Vs[r][c + 1] = (__bf16)x.y;
            Vs[r][c + 2] = (__bf16)x.z; Vs[r][c + 3] = (__bf16)x.w;
        }
    }
    __syncthreads();
    const int lane = tid & 63, w = tid >> 6;
    const int g = lane >> 4, li = lane & 15;
    bf16x8* dst = vf + ((size_t)b * NKBLK + kblk) * 8 * 64;
    #pragma unroll
    for (int jj = 0; jj < 2; ++jj) {
        const int dt = 2 * w + jj;
        bf16x8 v;
        #pragma unroll
        for (int e = 0; e < 8; ++e) v[e] = Vs[g * 8 + e][dt * 16 + li];
        dst[dt * 64 + lane] = v;
    }
}

// ==== attn_fused: K-split 2-way, 16 waves/CU, barrier-free loops, 2-pass ====
__global__ __launch_bounds__(128, 4)
void attn_fused(const float* __restrict__ qg,
                const bf16x8* __restrict__ kf,
                const bf16x8* __restrict__ vf,
                const int* __restrict__ maskg,
                float* __restrict__ og,
                float* __restrict__ wg)
{
    __shared__ __align__(16) __bf16 P[2][16][40];      // 2.5 KB
    __shared__ unsigned char MB[NKBLK][64];            // 4 KB (waves cover disjoint kblk)
    __shared__ __align__(16) float Wst[2][16][36];     // 4.6 KB
    __shared__ float Osum[16 * DIM];                   // 8 KB
    __shared__ float rowpart[2][16];
    __shared__ float rinvS[16];

    const int tid  = threadIdx.x;
    const int wave = tid >> 6;     // 0..1 : K-half owner
    const int lane = tid & 63;
    const int g    = lane >> 4;
    const int li   = lane & 15;

    // XCD pinning: batch b -> xcd b%8
    const int wgid = blockIdx.x;           // 0..2047
    const int xcd  = wgid & 7;
    const int rest = wgid >> 3;            // 0..255
    const int b    = xcd + 8 * (rest & 1);
    const int qt16 = rest >> 1;            // 0..127
    const int q0   = qt16 * 16;            // block's 16 queries (shared by both waves)
    const int kbase = wave * 32;           // this wave's kblk range [kbase, kbase+32)

    const size_t bb = (size_t)b * LSEQ;

    // zero O accumulator (ordered before atomics by the post-pass1 barrier)
    for (int i = tid; i < 16 * DIM; i += 128) Osum[i] = 0.0f;

    // Q fragments with scale*log2(e)
    const float qscale = 0.08838834764831845f * 1.4426950408889634f;
    bf16x8 qf[4];
    {
        const float* qrow = qg + (bb + q0 + li) * DIM + g * 8;
        #pragma unroll
        for (int d = 0; d < 4; ++d) {
            const float4* p4 = reinterpret_cast<const float4*>(qrow + d * 32);
            float4 x = p4[0];
            float4 y = p4[1];
            x.x *= qscale; x.y *= qscale; x.z *= qscale; x.w *= qscale;
            y.x *= qscale; y.y *= qscale; y.z *= qscale; y.w *= qscale;
            qf[d] = cvt8(x, y);
        }
    }

    float rsum[4] = {0.f, 0.f, 0.f, 0.f};
    f32x4 accO[8];
    #pragma unroll
    for (int i = 0; i < 8; ++i) accO[i] = (f32x4){0.f, 0.f, 0.f, 0.f};

    const bf16x8* KbL = kf + (size_t)b * NKBLK * 512 + lane;   // lane-indexed K frags
    const bf16x8* VbL = vf + (size_t)b * NKBLK * 512 + lane;   // lane-indexed V frags
    // mask in fragment order: element (t2,r) at kblk = mpQ[r*LSEQ + kblk*32 + t2*16]
    const int* mpQ = maskg + (bb + q0 + g * 4) * (size_t)LSEQ + li;

    // ================= PASS 1: partial rowsum + PV (barrier-free loop) =================
    int mcur[8], mnxt[8];
    #pragma unroll
    for (int j = 0; j < 8; ++j) {
        const int t2 = j >> 2, r = j & 3;
        mcur[j] = mpQ[(size_t)r * LSEQ + kbase * 32 + t2 * 16];
    }

    for (int it = 0; it < 32; ++it) {
        const int kblk = kbase + it;

        // K and V fragments direct from packed workspace (L1/L2-served)
        bf16x8 kc[8], vc[8];
        #pragma unroll
        for (int j = 0; j < 8; ++j) kc[j] = KbL[(size_t)kblk * 512 + j * 64];
        #pragma unroll
        for (int dt = 0; dt < 8; ++dt) vc[dt] = VbL[(size_t)kblk * 512 + dt * 64];

        // prefetch mask for it+1
        if (it + 1 < 32) {
            #pragma unroll
            for (int j = 0; j < 8; ++j) {
                const int t2 = j >> 2, r = j & 3;
                mnxt[j] = mpQ[(size_t)r * LSEQ + (kblk + 1) * 32 + t2 * 16];
            }
        }

        // QK^T
        f32x4 s0 = (f32x4){0.f, 0.f, 0.f, 0.f};
        f32x4 s1 = (f32x4){0.f, 0.f, 0.f, 0.f};
        #pragma unroll
        for (int d = 0; d < 4; ++d) {
            s0 = __builtin_amdgcn_mfma_f32_16x16x32_bf16(qf[d], kc[d],     s0, 0, 0, 0);
            s1 = __builtin_amdgcn_mfma_f32_16x16x32_bf16(qf[d], kc[4 + d], s1, 0, 0, 0);
        }

        // mask + exp2 + P stage + rowsum; pack byte for pass 2
        unsigned byte = 0;
        #pragma unroll
        for (int t2 = 0; t2 < 2; ++t2) {
            f32x4 sv = t2 ? s1 : s0;
            #pragma unroll
            for (int r = 0; r < 4; ++r) {
                const int j = t2 * 4 + r;
                const bool msk = (mcur[j] != 0);
                byte |= (msk ? 1u : 0u) << j;
                float sc = msk ? -1.0e9f : sv[r];
                float ev = __builtin_amdgcn_exp2f(sc);
                rsum[r] += ev;
                P[wave][g * 4 + r][t2 * 16 + li] = (__bf16)ev;
            }
        }
        MB[kblk][lane] = (unsigned char)byte;

        // PV (same-wave P round-trip, in-order LDS)
        {
            bf16x8 af = *reinterpret_cast<const bf16x8*>(&P[wave][li][g * 8]);
            #pragma unroll
            for (int dt = 0; dt < 8; ++dt)
                accO[dt] = __builtin_amdgcn_mfma_f32_16x16x32_bf16(af, vc[dt], accO[dt], 0, 0, 0);
        }

        #pragma unroll
        for (int j = 0; j < 8; ++j) mcur[j] = mnxt[j];
    }

    // partial rowsum reduce across li lanes (stays within lane group)
    #pragma unroll
    for (int off = 1; off < 16; off <<= 1) {
        #pragma unroll
        for (int r = 0; r < 4; ++r) rsum[r] += __shfl_xor(rsum[r], off, 64);
    }
    if (li == 0) {
        #pragma unroll
        for (int r = 0; r < 4; ++r) rowpart[wave][g * 4 + r] = rsum[r];
    }
    __syncthreads();   // zero-init + rowpart + both waves' pass-1 done

    // combine O partials across the 2 K-half waves
    #pragma unroll
    for (int dt = 0; dt < 8; ++dt)
        #pragma unroll
        for (int r = 0; r < 4; ++r)
            atomicAdd(&Osum[(g * 4 + r) * DIM + dt * 16 + li], accO[dt][r]);
    if (tid < 16) {
        // rowpart written by li==0 lanes; barrier above ordered it
        // (rsum combine happens after the atomics barrier below uses rinvS)
        rinvS[tid] = 1.0f / (rowpart[0][tid] + rowpart[1][tid]);
    }
    __syncthreads();   // Osum complete, rinvS complete

    float rinv[4];
    #pragma unroll
    for (int r = 0; r < 4; ++r) rinv[r] = rinvS[g * 4 + r];

    // O write: coalesced f32x4 nt, both waves share the work
    {
        float* ob = og + (bb + q0) * DIM;
        const f32x4* os4 = reinterpret_cast<const f32x4*>(Osum);
        #pragma unroll
        for (int u = 0; u < 4; ++u) {
            const int i4 = u * 128 + tid;           // 512 units total
            const int row = i4 >> 5;
            f32x4 x = os4[i4];
            const float inv = rinvS[row];
            x[0] *= inv; x[1] *= inv; x[2] *= inv; x[3] *= inv;
            __builtin_nontemporal_store(x, reinterpret_cast<f32x4*>(ob + i4 * 4));
        }
    }

    // ====== PASS 2: barrier-free; K frags unroll-2 dbuf; full-line W stores ======
    float* wrow = wg + (bb + q0) * (size_t)LSEQ;

    auto w_iter = [&](int kblk, bf16x8* kc) {
        const unsigned byte = MB[kblk][lane];   // same-wave rows, in-order

        f32x4 s0 = (f32x4){0.f, 0.f, 0.f, 0.f};
        f32x4 s1 = (f32x4){0.f, 0.f, 0.f, 0.f};
        #pragma unroll
        for (int d = 0; d < 4; ++d) {
            s0 = __builtin_amdgcn_mfma_f32_16x16x32_bf16(qf[d], kc[d],     s0, 0, 0, 0);
            s1 = __builtin_amdgcn_mfma_f32_16x16x32_bf16(qf[d], kc[4 + d], s1, 0, 0, 0);
        }

        // stage W tile in LDS (per-wave, same-wave in-order: no barrier)
        #pragma unroll
        for (int t2 = 0; t2 < 2; ++t2) {
            f32x4 sv = t2 ? s1 : s0;
            #pragma unroll
            for (int r = 0; r < 4; ++r) {
                float sc = ((byte >> (t2 * 4 + r)) & 1u) ? -1.0e9f : sv[r];
                Wst[wave][g * 4 + r][t2 * 16 + li] =
                    __builtin_amdgcn_exp2f(sc) * rinv[r];
            }
        }

        // full-line W write: 8 lanes x 16B = one contiguous 128B line per row
        #pragma unroll
        for (int p2 = 0; p2 < 2; ++p2) {
            const int row = p2 * 8 + (lane >> 3);
            const int col = (lane & 7) * 4;
            f32x4 wv = *reinterpret_cast<const f32x4*>(&Wst[wave][row][col]);
            __builtin_nontemporal_store(wv,
                reinterpret_cast<f32x4*>(wrow + (size_t)row * LSEQ + kblk * 32 + col));
        }
    };

    bf16x8 kA[8], kB[8];
    #pragma unroll
    for (int j = 0; j < 8; ++j) kA[j] = KbL[(size_t)kbase * 512 + j * 64];
    for (int it = 0; it < 32; it += 2) {
        const int kblk = kbase + it;
        #pragma unroll
        for (int j = 0; j < 8; ++j) kB[j] = KbL[(size_t)(kblk + 1) * 512 + j * 64];
        w_iter(kblk, kA);
        if (it + 2 < 32) {
            #pragma unroll
            for (int j = 0; j < 8; ++j) kA[j] = KbL[(size_t)(kblk + 2) * 512 + j * 64];
        }
        w_iter(kblk + 1, kB);
    }
}

// ========================= fallback (no workspace) =========================
__global__ __launch_bounds__(256, 2)
void sdpa_fused_plain(const float* __restrict__ qg,
                      const float* __restrict__ kg,
                      const float* __restrict__ vg,
                      const int*   __restrict__ maskg,
                      float* __restrict__ og,
                      float* __restrict__ wg)
{
    __shared__ __align__(16) __bf16 Es[16 * EPITCH];
    __shared__ float Osum[16 * DIM];
    __shared__ float rowpart[4][16];
    __shared__ float rowinv[16];

    const int tid  = threadIdx.x;
    const int wave = tid >> 6;
    const int lane = tid & 63;
    const int g    = lane >> 4;
    const int li   = lane & 15;
    const int qt = blockIdx.x;
    const int b  = blockIdx.y;
    const int q0 = qt * 16;

    for (int i = tid; i < 16 * DIM; i += 256) Osum[i] = 0.0f;

    const float qscale = 0.08838834764831845f * 1.4426950408889634f;
    bf16x8 qf[4];
    {
        const float* qrow = qg + ((size_t)b * LSEQ + q0 + li) * DIM + g * 8;
        #pragma unroll
        for (int d = 0; d < 4; ++d) {
            const float4* p4 = reinterpret_cast<const float4*>(qrow + d * 32);
            float4 x = p4[0];
            float4 y = p4[1];
            x.x *= qscale; x.y *= qscale; x.z *= qscale; x.w *= qscale;
            y.x *= qscale; y.y *= qscale; y.z *= qscale; y.w *= qscale;
            qf[d] = cvt8(x, y);
        }
    }

    float rsum[4] = {0.f, 0.f, 0.f, 0.f};
    f32x4 accO[8];
    #pragma unroll
    for (int i = 0; i < 8; ++i) accO[i] = (f32x4){0.f, 0.f, 0.f, 0.f};

    const int kwave0 = wave * 512;
    const size_t browbase = (size_t)b * LSEQ;

    for (int it = 0; it < 16; ++it) {
        const int kb = kwave0 + it * 32;
        f32x4 s0 = (f32x4){0.f, 0.f, 0.f, 0.f};
        f32x4 s1 = (f32x4){0.f, 0.f, 0.f, 0.f};
        {
            const float* kp0 = kg + (browbase + kb + li) * DIM + g * 8;
            const float* kp1 = kp0 + (size_t)16 * DIM;
            #pragma unroll
            for (int d = 0; d < 4; ++d) {
                const float4* a4 = reinterpret_cast<const float4*>(kp0 + d * 32);
                const float4* b4 = reinterpret_cast<const float4*>(kp1 + d * 32);
                s0 = __builtin_amdgcn_mfma_f32_16x16x32_bf16(qf[d], cvt8(a4[0], a4[1]), s0, 0, 0, 0);
                s1 = __builtin_amdgcn_mfma_f32_16x16x32_bf16(qf[d], cvt8(b4[0], b4[1]), s1, 0, 0, 0);
            }
        }
        const int* mbase = maskg + (browbase + q0) * LSEQ + kb + li;
        #pragma unroll
        for (int t = 0; t < 2; ++t) {
            f32x4 sv = t ? s1 : s0;
            const int col = kb + t * 16 + li;
            #pragma unroll
            for (int r = 0; r < 4; ++r) {
                const int m = mbase[(size_t)(g * 4 + r) * LSEQ + t * 16];
                float sc = m ? -1.0e9f : sv[r];
                float ev = __builtin_amdgcn_exp2f(sc);
                rsum[r] += ev;
                Es[(g * 4 + r) * EPITCH + col] = (__bf16)ev;
            }
        }
        bf16x8 af = *reinterpret_cast<const bf16x8*>(&Es[li * EPITCH + kb + g * 8]);
        const float* vb = vg + (browbase + kb + g * 8) * DIM + li;
        #pragma unroll
        for (int dt = 0; dt < 8; ++dt) {
            const float* vp = vb + dt * 16;
            bf16x8 bf;
            #pragma unroll
            for (int j = 0; j < 8; ++j) bf[j] = (__bf16)vp[(size_t)j * DIM];
            accO[dt] = __builtin_amdgcn_mfma_f32_16x16x32_bf16(af, bf, accO[dt], 0, 0, 0);
        }
    }

    #pragma unroll
    for (int off = 1; off < 16; off <<= 1) {
        #pragma unroll
        for (int r = 0; r < 4; ++r) rsum[r] += __shfl_xor(rsum[r], off, 64);
    }
    if (li == 0) {
        #pragma unroll
        for (int r = 0; r < 4; ++r) rowpart[wave][g * 4 + r] = rsum[r];
    }
    __syncthreads();
    #pragma unroll
    for (int dt = 0; dt < 8; ++dt) {
        #pragma unroll
        for (int r = 0; r < 4; ++r)
            atomicAdd(&Osum[(g * 4 + r) * DIM + dt * 16 + li], accO[dt][r]);
    }
    if (tid < 16) {
        float s = rowpart[0][tid] + rowpart[1][tid] + rowpart[2][tid] + rowpart[3][tid];
        rowinv[tid] = 1.0f / s;
    }
    __syncthreads();

    const size_t wbase = (browbase + q0) * LSEQ;
    for (int i = tid; i < 16 * (LSEQ / 8); i += 256) {
        const int row = i >> 8;
        const int col = (i & 255) * 8;
        bf16x8 e = *reinterpret_cast<const bf16x8*>(&Es[row * EPITCH + col]);
        const float inv = rowinv[row];
        float4 w0, w1;
        w0.x = (float)e[0] * inv; w0.y = (float)e[1] * inv;
        w0.z = (float)e[2] * inv; w0.w = (float)e[3] * inv;
        w1.x = (float)e[4] * inv; w1.y = (float)e[5] * inv;
        w1.z = (float)e[6] * inv; w1.w = (float)e[7] * inv;
        float* dst = wg + wbase + (size_t)row * LSEQ + col;
        *reinterpret_cast<float4*>(dst)     = w0;
        *reinterpret_cast<float4*>(dst + 4) = w1;
    }
    const size_t obase = (browbase + q0) * DIM;
    for (int i = tid; i < 16 * DIM; i += 256) {
        const int row = i >> 7;
        og[obase + i] = Osum[i] * rowinv[row];
    }
}

extern "C" void kernel_launch(void* const* d_in, const int* in_sizes, int n_in,
                              void* d_out, int out_size, void* d_ws, size_t ws_size,
                              hipStream_t stream) {
    const float* q    = (const float*)d_in[0];
    const float* k    = (const float*)d_in[1];
    const float* v    = (const float*)d_in[2];
    const int*   mask = (const int*)d_in[3];
    float* o = (float*)d_out;
    float* w = (float*)d_out + (size_t)BATCH * LSEQ * DIM;

    const size_t kfSize = (size_t)BATCH * NKBLK * 8 * 64 * sizeof(bf16x8);   // 8.4 MB
    const size_t vfSize = kfSize;                                            // 8.4 MB
    const size_t need   = kfSize + vfSize;                                   // 16.8 MB

    if (ws_size >= need) {
        bf16x8* kf  = (bf16x8*)d_ws;
        bf16x8* vfp = (bf16x8*)((char*)d_ws + kfSize);
        pack_k_kernel<<<dim3(NKBLK, BATCH), 256, 0, stream>>>(k, kf);
        pack_v_kernel<<<dim3(NKBLK, BATCH), 256, 0, stream>>>(v, vfp);
        attn_fused<<<2048, 128, 0, stream>>>(q, kf, vfp, mask, o, w);
    } else {
        dim3 grid(LSEQ / 16, BATCH);
        sdpa_fused_plain<<<grid, 256, 0, stream>>>(q, k, v, mask, o, w);
    }
}

// Round 16
// 218.036 us; speedup vs baseline: 1.2968x; 1.2968x over previous
//
#include <hip/hip_runtime.h>
#include <hip/hip_bf16.h>

typedef __attribute__((ext_vector_type(8))) __bf16 bf16x8;
typedef __attribute__((ext_vector_type(4))) float f32x4;

#define BATCH 16
#define LSEQ 2048
#define DIM 128
#define EPITCH 2056
#define NKBLK 64   // 2048 / 32

__device__ __forceinline__ bf16x8 cvt8(float4 a, float4 b) {
    bf16x8 r;
    r[0] = (__bf16)a.x; r[1] = (__bf16)a.y; r[2] = (__bf16)a.z; r[3] = (__bf16)a.w;
    r[4] = (__bf16)b.x; r[5] = (__bf16)b.y; r[6] = (__bf16)b.z; r[7] = (__bf16)b.w;
    return r;
}

// ============ preproc: K -> fragment-blocked Kf[b][kblk][j][lane] ============
__global__ __launch_bounds__(256)
void pack_k_kernel(const float* __restrict__ kg, bf16x8* __restrict__ kf) {
    __shared__ __bf16 Ks[32][DIM + 8];
    const int kblk = blockIdx.x, b = blockIdx.y;
    const int tid = threadIdx.x;
    {
        const int r = tid >> 3, c4 = tid & 7;
        const float* src = kg + ((size_t)b * LSEQ + kblk * 32 + r) * DIM;
        #pragma unroll
        for (int jj = 0; jj < 4; ++jj) {
            const int c = (c4 + 8 * jj) * 4;
            float4 x = *reinterpret_cast<const float4*>(src + c);
            Ks[r][c + 0] = (__bf16)x.x; Ks[r][c + 1] = (__bf16)x.y;
            Ks[r][c + 2] = (__bf16)x.z; Ks[r][c + 3] = (__bf16)x.w;
        }
    }
    __syncthreads();
    const int lane = tid & 63, w = tid >> 6;
    const int g = lane >> 4, li = lane & 15;
    bf16x8* dst = kf + ((size_t)b * NKBLK + kblk) * 8 * 64;
    #pragma unroll
    for (int jj = 0; jj < 2; ++jj) {
        const int j = 2 * w + jj;
        const int t = j >> 2, d = j & 3;
        bf16x8 v;
        #pragma unroll
        for (int e = 0; e < 8; ++e) v[e] = Ks[t * 16 + li][d * 32 + g * 8 + e];
        dst[j * 64 + lane] = v;
    }
}

// ============ preproc: V -> fragment-blocked Vf[b][kblk][dt][lane] ============
__global__ __launch_bounds__(256)
void pack_v_kernel(const float* __restrict__ vg, bf16x8* __restrict__ vf) {
    __shared__ __bf16 Vs[32][DIM + 8];
    const int kblk = blockIdx.x, b = blockIdx.y;
    const int tid = threadIdx.x;
    {
        const int r = tid >> 3, c4 = tid & 7;
        const float* src = vg + ((size_t)b * LSEQ + kblk * 32 + r) * DIM;
        #pragma unroll
        for (int jj = 0; jj < 4; ++jj) {
            const int c = (c4 + 8 * jj) * 4;
            float4 x = *reinterpret_cast<const float4*>(src + c);
            Vs[r][c + 0] = (__bf16)x.x; Vs[r][c + 1] = (__bf16)x.y;
            Vs[r][c + 2] = (__bf16)x.z; Vs[r][c + 3] = (__bf16)x.w;
        }
    }
    __syncthreads();
    const int lane = tid & 63, w = tid >> 6;
    const int g = lane >> 4, li = lane & 15;
    bf16x8* dst = vf + ((size_t)b * NKBLK + kblk) * 8 * 64;
    #pragma unroll
    for (int jj = 0; jj < 2; ++jj) {
        const int dt = 2 * w + jj;
        bf16x8 v;
        #pragma unroll
        for (int e = 0; e < 8; ++e) v[e] = Vs[g * 8 + e][dt * 16 + li];
        dst[dt * 64 + lane] = v;
    }
}

// ==== attn_fused: 32q/wave (2x16q sharing K/V), 2 K-halves, barrier-free loops ====
__global__ __launch_bounds__(256, 2)
void attn_fused(const float* __restrict__ qg,
                const bf16x8* __restrict__ kf,
                const bf16x8* __restrict__ vf,
                const int* __restrict__ maskg,
                float* __restrict__ og,
                float* __restrict__ wg)
{
    __shared__ __align__(16) __bf16 P[4][16][40];      // 5.1 KB
    __shared__ unsigned char MB[4][NKBLK][64];         // 16 KB (qsub x kblk x lane)
    __shared__ __align__(16) float Wst[4][16][36];     // 9.2 KB
    __shared__ float Osum[64 * DIM];                   // 32 KB
    __shared__ float rowpart[2][64];
    __shared__ float rinvS[64];

    const int tid  = threadIdx.x;
    const int wave = tid >> 6;     // 0..3
    const int lane = tid & 63;
    const int g    = lane >> 4;
    const int li   = lane & 15;
    const int qw   = wave >> 1;    // q-group 0/1 (32q each)
    const int kh   = wave & 1;     // K-half 0/1

    // XCD pinning: batch b -> xcd b%8
    const int wgid = blockIdx.x;           // 0..511
    const int xcd  = wgid & 7;
    const int rest = wgid >> 3;            // 0..63
    const int b    = xcd + 8 * (rest & 1);
    const int qb   = rest >> 1;            // 0..31 (64-query block)
    const int q0b  = qb * 64;
    const int q0w  = q0b + qw * 32;        // this wave's 32 queries
    const int kbase = kh * 32;             // this wave's kblk range

    const size_t bb = (size_t)b * LSEQ;

    for (int i = tid; i < 64 * DIM; i += 256) Osum[i] = 0.0f;

    // Q fragments for 2 subtiles, scale*log2(e) folded
    const float qscale = 0.08838834764831845f * 1.4426950408889634f;
    bf16x8 qf[2][4];
    #pragma unroll
    for (int s = 0; s < 2; ++s) {
        const float* qrow = qg + (bb + q0w + s * 16 + li) * DIM + g * 8;
        #pragma unroll
        for (int d = 0; d < 4; ++d) {
            const float4* p4 = reinterpret_cast<const float4*>(qrow + d * 32);
            float4 x = p4[0];
            float4 y = p4[1];
            x.x *= qscale; x.y *= qscale; x.z *= qscale; x.w *= qscale;
            y.x *= qscale; y.y *= qscale; y.z *= qscale; y.w *= qscale;
            qf[s][d] = cvt8(x, y);
        }
    }

    float rsum[2][4];
    #pragma unroll
    for (int s = 0; s < 2; ++s)
        #pragma unroll
        for (int r = 0; r < 4; ++r) rsum[s][r] = 0.0f;
    f32x4 accO[2][8];
    #pragma unroll
    for (int s = 0; s < 2; ++s)
        #pragma unroll
        for (int i = 0; i < 8; ++i) accO[s][i] = (f32x4){0.f, 0.f, 0.f, 0.f};

    const bf16x8* KbL = kf + (size_t)b * NKBLK * 512 + lane;
    const bf16x8* VbL = vf + (size_t)b * NKBLK * 512 + lane;
    const int* mpQ0 = maskg + (bb + q0w + g * 4) * (size_t)LSEQ + li;
    const int* mpQ1 = mpQ0 + (size_t)16 * LSEQ;

    // ================= PASS 1: partial rowsum + PV (barrier-free) =================
    for (int it = 0; it < 32; ++it) {
        const int kblk = kbase + it;

        bf16x8 kc[8], vc[8];
        #pragma unroll
        for (int j = 0; j < 8; ++j) kc[j] = KbL[(size_t)kblk * 512 + j * 64];
        #pragma unroll
        for (int dt = 0; dt < 8; ++dt) vc[dt] = VbL[(size_t)kblk * 512 + dt * 64];

        int m0[8], m1[8];
        #pragma unroll
        for (int j = 0; j < 8; ++j) {
            const int t2 = j >> 2, r = j & 3;
            m0[j] = mpQ0[(size_t)r * LSEQ + kblk * 32 + t2 * 16];
            m1[j] = mpQ1[(size_t)r * LSEQ + kblk * 32 + t2 * 16];
        }

        // QK^T: 2 subtiles share kc (16 MFMA)
        f32x4 sv[2][2];
        #pragma unroll
        for (int s = 0; s < 2; ++s)
            #pragma unroll
            for (int t2 = 0; t2 < 2; ++t2) sv[s][t2] = (f32x4){0.f, 0.f, 0.f, 0.f};
        #pragma unroll
        for (int d = 0; d < 4; ++d) {
            sv[0][0] = __builtin_amdgcn_mfma_f32_16x16x32_bf16(qf[0][d], kc[d],     sv[0][0], 0, 0, 0);
            sv[0][1] = __builtin_amdgcn_mfma_f32_16x16x32_bf16(qf[0][d], kc[4 + d], sv[0][1], 0, 0, 0);
            sv[1][0] = __builtin_amdgcn_mfma_f32_16x16x32_bf16(qf[1][d], kc[d],     sv[1][0], 0, 0, 0);
            sv[1][1] = __builtin_amdgcn_mfma_f32_16x16x32_bf16(qf[1][d], kc[4 + d], sv[1][1], 0, 0, 0);
        }

        // per subtile: mask + exp2 + P stage + rowsum + MB + PV (vc shared)
        #pragma unroll
        for (int s = 0; s < 2; ++s) {
            const int* mm = s ? m1 : m0;
            unsigned byte = 0;
            #pragma unroll
            for (int t2 = 0; t2 < 2; ++t2) {
                #pragma unroll
                for (int r = 0; r < 4; ++r) {
                    const int j = t2 * 4 + r;
                    const bool msk = (mm[j] != 0);
                    byte |= (msk ? 1u : 0u) << j;
                    float sc = msk ? -1.0e9f : sv[s][t2][r];
                    float ev = __builtin_amdgcn_exp2f(sc);
                    rsum[s][r] += ev;
                    P[wave][g * 4 + r][t2 * 16 + li] = (__bf16)ev;
                }
            }
            MB[qw * 2 + s][kblk][lane] = (unsigned char)byte;

            bf16x8 af = *reinterpret_cast<const bf16x8*>(&P[wave][li][g * 8]);
            #pragma unroll
            for (int dt = 0; dt < 8; ++dt)
                accO[s][dt] = __builtin_amdgcn_mfma_f32_16x16x32_bf16(af, vc[dt], accO[s][dt], 0, 0, 0);
        }
    }

    // partial rowsum reduce across li lanes
    #pragma unroll
    for (int off = 1; off < 16; off <<= 1) {
        #pragma unroll
        for (int s = 0; s < 2; ++s)
            #pragma unroll
            for (int r = 0; r < 4; ++r) rsum[s][r] += __shfl_xor(rsum[s][r], off, 64);
    }
    if (li == 0) {
        #pragma unroll
        for (int s = 0; s < 2; ++s)
            #pragma unroll
            for (int r = 0; r < 4; ++r)
                rowpart[kh][qw * 32 + s * 16 + g * 4 + r] = rsum[s][r];
    }
    __syncthreads();   // Osum zero-init + rowpart + all pass-1 done

    // combine O partials across the 2 K-half waves
    #pragma unroll
    for (int s = 0; s < 2; ++s)
        #pragma unroll
        for (int dt = 0; dt < 8; ++dt)
            #pragma unroll
            for (int r = 0; r < 4; ++r)
                atomicAdd(&Osum[(qw * 32 + s * 16 + g * 4 + r) * DIM + dt * 16 + li],
                          accO[s][dt][r]);
    if (tid < 64)
        rinvS[tid] = 1.0f / (rowpart[0][tid] + rowpart[1][tid]);
    __syncthreads();   // Osum + rinvS complete

    float rinv[2][4];
    #pragma unroll
    for (int s = 0; s < 2; ++s)
        #pragma unroll
        for (int r = 0; r < 4; ++r)
            rinv[s][r] = rinvS[qw * 32 + s * 16 + g * 4 + r];

    // O write: coalesced f32x4 nt (64 rows x 128)
    {
        float* ob = og + (bb + q0b) * DIM;
        const f32x4* os4 = reinterpret_cast<const f32x4*>(Osum);
        #pragma unroll
        for (int u = 0; u < 8; ++u) {
            const int i4 = u * 256 + tid;          // 2048 units
            const int row = i4 >> 5;
            f32x4 x = os4[i4];
            const float inv = rinvS[row];
            x[0] *= inv; x[1] *= inv; x[2] *= inv; x[3] *= inv;
            __builtin_nontemporal_store(x, reinterpret_cast<f32x4*>(ob + i4 * 4));
        }
    }

    // ====== PASS 2: barrier-free; recompute QK^T, write W full-line ======
    for (int it = 0; it < 32; ++it) {
        const int kblk = kbase + it;

        bf16x8 kc[8];
        #pragma unroll
        for (int j = 0; j < 8; ++j) kc[j] = KbL[(size_t)kblk * 512 + j * 64];

        f32x4 sv[2][2];
        #pragma unroll
        for (int s = 0; s < 2; ++s)
            #pragma unroll
            for (int t2 = 0; t2 < 2; ++t2) sv[s][t2] = (f32x4){0.f, 0.f, 0.f, 0.f};
        #pragma unroll
        for (int d = 0; d < 4; ++d) {
            sv[0][0] = __builtin_amdgcn_mfma_f32_16x16x32_bf16(qf[0][d], kc[d],     sv[0][0], 0, 0, 0);
            sv[0][1] = __builtin_amdgcn_mfma_f32_16x16x32_bf16(qf[0][d], kc[4 + d], sv[0][1], 0, 0, 0);
            sv[1][0] = __builtin_amdgcn_mfma_f32_16x16x32_bf16(qf[1][d], kc[d],     sv[1][0], 0, 0, 0);
            sv[1][1] = __builtin_amdgcn_mfma_f32_16x16x32_bf16(qf[1][d], kc[4 + d], sv[1][1], 0, 0, 0);
        }

        #pragma unroll
        for (int s = 0; s < 2; ++s) {
            const unsigned byte = MB[qw * 2 + s][kblk][lane];
            #pragma unroll
            for (int t2 = 0; t2 < 2; ++t2) {
                #pragma unroll
                for (int r = 0; r < 4; ++r) {
                    float sc = ((byte >> (t2 * 4 + r)) & 1u) ? -1.0e9f : sv[s][t2][r];
                    Wst[wave][g * 4 + r][t2 * 16 + li] =
                        __builtin_amdgcn_exp2f(sc) * rinv[s][r];
                }
            }
            float* wrow = wg + (bb + q0w + s * 16) * (size_t)LSEQ;
            #pragma unroll
            for (int pp = 0; pp < 2; ++pp) {
                const int row = pp * 8 + (lane >> 3);
                const int col = (lane & 7) * 4;
                f32x4 wv = *reinterpret_cast<const f32x4*>(&Wst[wave][row][col]);
                __builtin_nontemporal_store(wv,
                    reinterpret_cast<f32x4*>(wrow + (size_t)row * LSEQ + kblk * 32 + col));
            }
        }
    }
}

// ========================= fallback (no workspace) =========================
__global__ __launch_bounds__(256, 2)
void sdpa_fused_plain(const float* __restrict__ qg,
                      const float* __restrict__ kg,
                      const float* __restrict__ vg,
                      const int*   __restrict__ maskg,
                      float* __restrict__ og,
                      float* __restrict__ wg)
{
    __shared__ __align__(16) __bf16 Es[16 * EPITCH];
    __shared__ float Osum[16 * DIM];
    __shared__ float rowpart[4][16];
    __shared__ float rowinv[16];

    const int tid  = threadIdx.x;
    const int wave = tid >> 6;
    const int lane = tid & 63;
    const int g    = lane >> 4;
    const int li   = lane & 15;
    const int qt = blockIdx.x;
    const int b  = blockIdx.y;
    const int q0 = qt * 16;

    for (int i = tid; i < 16 * DIM; i += 256) Osum[i] = 0.0f;

    const float qscale = 0.08838834764831845f * 1.4426950408889634f;
    bf16x8 qf[4];
    {
        const float* qrow = qg + ((size_t)b * LSEQ + q0 + li) * DIM + g * 8;
        #pragma unroll
        for (int d = 0; d < 4; ++d) {
            const float4* p4 = reinterpret_cast<const float4*>(qrow + d * 32);
            float4 x = p4[0];
            float4 y = p4[1];
            x.x *= qscale; x.y *= qscale; x.z *= qscale; x.w *= qscale;
            y.x *= qscale; y.y *= qscale; y.z *= qscale; y.w *= qscale;
            qf[d] = cvt8(x, y);
        }
    }

    float rsum[4] = {0.f, 0.f, 0.f, 0.f};
    f32x4 accO[8];
    #pragma unroll
    for (int i = 0; i < 8; ++i) accO[i] = (f32x4){0.f, 0.f, 0.f, 0.f};

    const int kwave0 = wave * 512;
    const size_t browbase = (size_t)b * LSEQ;

    for (int it = 0; it < 16; ++it) {
        const int kb = kwave0 + it * 32;
        f32x4 s0 = (f32x4){0.f, 0.f, 0.f, 0.f};
        f32x4 s1 = (f32x4){0.f, 0.f, 0.f, 0.f};
        {
            const float* kp0 = kg + (browbase + kb + li) * DIM + g * 8;
            const float* kp1 = kp0 + (size_t)16 * DIM;
            #pragma unroll
            for (int d = 0; d < 4; ++d) {
                const float4* a4 = reinterpret_cast<const float4*>(kp0 + d * 32);
                const float4* b4 = reinterpret_cast<const float4*>(kp1 + d * 32);
                s0 = __builtin_amdgcn_mfma_f32_16x16x32_bf16(qf[d], cvt8(a4[0], a4[1]), s0, 0, 0, 0);
                s1 = __builtin_amdgcn_mfma_f32_16x16x32_bf16(qf[d], cvt8(b4[0], b4[1]), s1, 0, 0, 0);
            }
        }
        const int* mbase = maskg + (browbase + q0) * LSEQ + kb + li;
        #pragma unroll
        for (int t = 0; t < 2; ++t) {
            f32x4 sv = t ? s1 : s0;
            const int col = kb + t * 16 + li;
            #pragma unroll
            for (int r = 0; r < 4; ++r) {
                const int m = mbase[(size_t)(g * 4 + r) * LSEQ + t * 16];
                float sc = m ? -1.0e9f : sv[r];
                float ev = __builtin_amdgcn_exp2f(sc);
                rsum[r] += ev;
                Es[(g * 4 + r) * EPITCH + col] = (__bf16)ev;
            }
        }
        bf16x8 af = *reinterpret_cast<const bf16x8*>(&Es[li * EPITCH + kb + g * 8]);
        const float* vb = vg + (browbase + kb + g * 8) * DIM + li;
        #pragma unroll
        for (int dt = 0; dt < 8; ++dt) {
            const float* vp = vb + dt * 16;
            bf16x8 bf;
            #pragma unroll
            for (int j = 0; j < 8; ++j) bf[j] = (__bf16)vp[(size_t)j * DIM];
            accO[dt] = __builtin_amdgcn_mfma_f32_16x16x32_bf16(af, bf, accO[dt], 0, 0, 0);
        }
    }

    #pragma unroll
    for (int off = 1; off < 16; off <<= 1) {
        #pragma unroll
        for (int r = 0; r < 4; ++r) rsum[r] += __shfl_xor(rsum[r], off, 64);
    }
    if (li == 0) {
        #pragma unroll
        for (int r = 0; r < 4; ++r) rowpart[wave][g * 4 + r] = rsum[r];
    }
    __syncthreads();
    #pragma unroll
    for (int dt = 0; dt < 8; ++dt) {
        #pragma unroll
        for (int r = 0; r < 4; ++r)
            atomicAdd(&Osum[(g * 4 + r) * DIM + dt * 16 + li], accO[dt][r]);
    }
    if (tid < 16) {
        float s = rowpart[0][tid] + rowpart[1][tid] + rowpart[2][tid] + rowpart[3][tid];
        rowinv[tid] = 1.0f / s;
    }
    __syncthreads();

    const size_t wbase = (browbase + q0) * LSEQ;
    for (int i = tid; i < 16 * (LSEQ / 8); i += 256) {
        const int row = i >> 8;
        const int col = (i & 255) * 8;
        bf16x8 e = *reinterpret_cast<const bf16x8*>(&Es[row * EPITCH + col]);
        const float inv = rowinv[row];
        float4 w0, w1;
        w0.x = (float)e[0] * inv; w0.y = (float)e[1] * inv;
        w0.z = (float)e[2] * inv; w0.w = (float)e[3] * inv;
        w1.x = (float)e[4] * inv; w1.y = (float)e[5] * inv;
        w1.z = (float)e[6] * inv; w1.w = (float)e[7] * inv;
        float* dst = wg + wbase + (size_t)row * LSEQ + col;
        *reinterpret_cast<float4*>(dst)     = w0;
        *reinterpret_cast<float4*>(dst + 4) = w1;
    }
    const size_t obase = (browbase + q0) * DIM;
    for (int i = tid; i < 16 * DIM; i += 256) {
        const int row = i >> 7;
        og[obase + i] = Osum[i] * rowinv[row];
    }
}

extern "C" void kernel_launch(void* const* d_in, const int* in_sizes, int n_in,
                              void* d_out, int out_size, void* d_ws, size_t ws_size,
                              hipStream_t stream) {
    const float* q    = (const float*)d_in[0];
    const float* k    = (const float*)d_in[1];
    const float* v    = (const float*)d_in[2];
    const int*   mask = (const int*)d_in[3];
    float* o = (float*)d_out;
    float* w = (float*)d_out + (size_t)BATCH * LSEQ * DIM;

    const size_t kfSize = (size_t)BATCH * NKBLK * 8 * 64 * sizeof(bf16x8);   // 8.4 MB
    const size_t vfSize = kfSize;                                            // 8.4 MB
    const size_t need   = kfSize + vfSize;                                   // 16.8 MB

    if (ws_size >= need) {
        bf16x8* kf  = (bf16x8*)d_ws;
        bf16x8* vfp = (bf16x8*)((char*)d_ws + kfSize);
        pack_k_kernel<<<dim3(NKBLK, BATCH), 256, 0, stream>>>(k, kf);
        pack_v_kernel<<<dim3(NKBLK, BATCH), 256, 0, stream>>>(v, vfp);
        attn_fused<<<512, 256, 0, stream>>>(q, kf, vfp, mask, o, w);
    } else {
        dim3 grid(LSEQ / 16, BATCH);
        sdpa_fused_plain<<<grid, 256, 0, stream>>>(q, k, v, mask, o, w);
    }
}

// Round 17
// 218.034 us; speedup vs baseline: 1.2968x; 1.0000x over previous
//
#include <hip/hip_runtime.h>
#include <hip/hip_bf16.h>

typedef __attribute__((ext_vector_type(8))) __bf16 bf16x8;
typedef __attribute__((ext_vector_type(4))) float f32x4;

#define BATCH 16
#define LSEQ 2048
#define DIM 128
#define EPITCH 2056
#define NKBLK 64   // 2048 / 32
#define NQROW (BATCH * LSEQ)   // 32768

__device__ __forceinline__ bf16x8 cvt8(float4 a, float4 b) {
    bf16x8 r;
    r[0] = (__bf16)a.x; r[1] = (__bf16)a.y; r[2] = (__bf16)a.z; r[3] = (__bf16)a.w;
    r[4] = (__bf16)b.x; r[5] = (__bf16)b.y; r[6] = (__bf16)b.z; r[7] = (__bf16)b.w;
    return r;
}

// ============ preproc: K -> fragment-blocked Kf[b][kblk][j][lane] ============
__global__ __launch_bounds__(256)
void pack_k_kernel(const float* __restrict__ kg, bf16x8* __restrict__ kf) {
    __shared__ __bf16 Ks[32][DIM + 8];
    const int kblk = blockIdx.x, b = blockIdx.y;
    const int tid = threadIdx.x;
    {
        const int r = tid >> 3, c4 = tid & 7;
        const float* src = kg + ((size_t)b * LSEQ + kblk * 32 + r) * DIM;
        #pragma unroll
        for (int jj = 0; jj < 4; ++jj) {
            const int c = (c4 + 8 * jj) * 4;
            float4 x = *reinterpret_cast<const float4*>(src + c);
            Ks[r][c + 0] = (__bf16)x.x; Ks[r][c + 1] = (__bf16)x.y;
            Ks[r][c + 2] = (__bf16)x.z; Ks[r][c + 3] = (__bf16)x.w;
        }
    }
    __syncthreads();
    const int lane = tid & 63, w = tid >> 6;
    const int g = lane >> 4, li = lane & 15;
    bf16x8* dst = kf + ((size_t)b * NKBLK + kblk) * 8 * 64;
    #pragma unroll
    for (int jj = 0; jj < 2; ++jj) {
        const int j = 2 * w + jj;
        const int t = j >> 2, d = j & 3;
        bf16x8 v;
        #pragma unroll
        for (int e = 0; e < 8; ++e) v[e] = Ks[t * 16 + li][d * 32 + g * 8 + e];
        dst[j * 64 + lane] = v;
    }
}

// ============ preproc: V -> fragment-blocked Vf[b][kblk][dt][lane] ============
__global__ __launch_bounds__(256)
void pack_v_kernel(const float* __restrict__ vg, bf16x8* __restrict__ vf) {
    __shared__ __bf16 Vs[32][DIM + 8];
    const int kblk = blockIdx.x, b = blockIdx.y;
    const int tid = threadIdx.x;
    {
        const int r = tid >> 3, c4 = tid & 7;
        const float* src = vg + ((size_t)b * LSEQ + kblk * 32 + r) * DIM;
        #pragma unroll
        for (int jj = 0; jj < 4; ++jj) {
            const int c = (c4 + 8 * jj) * 4;
            float4 x = *reinterpret_cast<const float4*>(src + c);
            Vs[r][c + 0] = (__bf16)x.x; Vs[r][c + 1] = (__bf16)x.y;
            Vs[r][c + 2] = (__bf16)x.z; Vs[r][c + 3] = (__bf16)x.w;
        }
    }
    __syncthreads();
    const int lane = tid & 63, w = tid >> 6;
    const int g = lane >> 4, li = lane & 15;
    bf16x8* dst = vf + ((size_t)b * NKBLK + kblk) * 8 * 64;
    #pragma unroll
    for (int jj = 0; jj < 2; ++jj) {
        const int dt = 2 * w + jj;
        bf16x8 v;
        #pragma unroll
        for (int e = 0; e < 8; ++e) v[e] = Vs[g * 8 + e][dt * 16 + li];
        dst[dt * 64 + lane] = v;
    }
}

// ============ attn1: 64q x half-K per block; partial O/rsum + mask bytes ============
__global__ __launch_bounds__(256, 4)
void attn1(const float* __restrict__ qg,
           const bf16x8* __restrict__ kf,
           const bf16x8* __restrict__ vf,
           const int* __restrict__ maskg,
           float* __restrict__ op_ws,          // [2][32768][128]
           float* __restrict__ rs_ws,          // [2][32768]
           unsigned char* __restrict__ mb_ws)  // [b][qt16][kblk][lane]
{
    __shared__ bf16x8 Kst[2][512];                     // 16 KB (dbuf K tile)
    __shared__ __align__(16) __bf16 P[4][16][40];      // 5.1 KB

    const int tid  = threadIdx.x;
    const int wave = tid >> 6;
    const int lane = tid & 63;
    const int g    = lane >> 4;
    const int li   = lane & 15;

    // XCD pinning: batch b -> xcd b%8
    const int wgid = blockIdx.x;           // 0..1023
    const int xcd  = wgid & 7;
    const int rest = wgid >> 3;            // 0..127
    const int b    = xcd + 8 * (rest & 1);
    const int r2   = rest >> 1;            // 0..63
    const int qb   = r2 >> 1;              // 0..31 (64-query block)
    const int kh   = r2 & 1;               // K half
    const int q0w  = qb * 64 + wave * 16;  // this wave's 16 queries
    const int qt16 = qb * 4 + wave;
    const int kb0  = kh * 32;              // first kblk of this half

    const size_t bb = (size_t)b * LSEQ;

    const float qscale = 0.08838834764831845f * 1.4426950408889634f;
    bf16x8 qf[4];
    {
        const float* qrow = qg + (bb + q0w + li) * DIM + g * 8;
        #pragma unroll
        for (int d = 0; d < 4; ++d) {
            const float4* p4 = reinterpret_cast<const float4*>(qrow + d * 32);
            float4 x = p4[0];
            float4 y = p4[1];
            x.x *= qscale; x.y *= qscale; x.z *= qscale; x.w *= qscale;
            y.x *= qscale; y.y *= qscale; y.z *= qscale; y.w *= qscale;
            qf[d] = cvt8(x, y);
        }
    }

    float rsum[4] = {0.f, 0.f, 0.f, 0.f};
    f32x4 accO[8];
    #pragma unroll
    for (int i = 0; i < 8; ++i) accO[i] = (f32x4){0.f, 0.f, 0.f, 0.f};

    const bf16x8* KbU = kf + (size_t)b * NKBLK * 512;
    const bf16x8* VbL = vf + (size_t)b * NKBLK * 512 + lane;
    const int* mpQ = maskg + (bb + q0w + g * 4) * (size_t)LSEQ + li;
    unsigned char* mbp = mb_ws + (((size_t)b * 128 + qt16) * NKBLK) * 64 + lane;

    bf16x8 ka = KbU[(size_t)kb0 * 512 + tid], kb2 = KbU[(size_t)kb0 * 512 + 256 + tid];
    int mcur[8], mnxt[8];
    #pragma unroll
    for (int j = 0; j < 8; ++j) {
        const int t2 = j >> 2, r = j & 3;
        mcur[j] = mpQ[(size_t)r * LSEQ + kb0 * 32 + t2 * 16];
    }

    for (int it = 0; it < 32; ++it) {
        const int kblk = kb0 + it;
        const int p = it & 1;
        Kst[p][tid] = ka; Kst[p][256 + tid] = kb2;
        __syncthreads();                   // single barrier (dbuf)

        bf16x8 kc[8];
        #pragma unroll
        for (int j = 0; j < 8; ++j) kc[j] = Kst[p][j * 64 + lane];

        bf16x8 vc[8];
        #pragma unroll
        for (int dt = 0; dt < 8; ++dt) vc[dt] = VbL[(size_t)kblk * 512 + dt * 64];

        if (it + 1 < 32) {
            const size_t un = (size_t)(kblk + 1) * 512;
            ka = KbU[un + tid];  kb2 = KbU[un + 256 + tid];
            #pragma unroll
            for (int j = 0; j < 8; ++j) {
                const int t2 = j >> 2, r = j & 3;
                mnxt[j] = mpQ[(size_t)r * LSEQ + (kblk + 1) * 32 + t2 * 16];
            }
        }

        f32x4 s0 = (f32x4){0.f, 0.f, 0.f, 0.f};
        f32x4 s1 = (f32x4){0.f, 0.f, 0.f, 0.f};
        #pragma unroll
        for (int d = 0; d < 4; ++d) {
            s0 = __builtin_amdgcn_mfma_f32_16x16x32_bf16(qf[d], kc[d],     s0, 0, 0, 0);
            s1 = __builtin_amdgcn_mfma_f32_16x16x32_bf16(qf[d], kc[4 + d], s1, 0, 0, 0);
        }

        unsigned byte = 0;
        #pragma unroll
        for (int t2 = 0; t2 < 2; ++t2) {
            f32x4 sv = t2 ? s1 : s0;
            #pragma unroll
            for (int r = 0; r < 4; ++r) {
                const int j = t2 * 4 + r;
                const bool msk = (mcur[j] != 0);
                byte |= (msk ? 1u : 0u) << j;
                float sc = msk ? -1.0e9f : sv[r];
                float ev = __builtin_amdgcn_exp2f(sc);
                rsum[r] += ev;
                P[wave][g * 4 + r][t2 * 16 + li] = (__bf16)ev;
            }
        }
        mbp[(size_t)kblk * 64] = (unsigned char)byte;

        {
            bf16x8 af = *reinterpret_cast<const bf16x8*>(&P[wave][li][g * 8]);
            #pragma unroll
            for (int dt = 0; dt < 8; ++dt)
                accO[dt] = __builtin_amdgcn_mfma_f32_16x16x32_bf16(af, vc[dt], accO[dt], 0, 0, 0);
        }

        #pragma unroll
        for (int j = 0; j < 8; ++j) mcur[j] = mnxt[j];
    }

    // intra-wave rowsum reduce
    #pragma unroll
    for (int off = 1; off < 16; off <<= 1) {
        #pragma unroll
        for (int r = 0; r < 4; ++r) rsum[r] += __shfl_xor(rsum[r], off, 64);
    }
    if (li == 0) {
        #pragma unroll
        for (int r = 0; r < 4; ++r)
            rs_ws[(size_t)kh * NQROW + bb + q0w + g * 4 + r] = rsum[r];
    }

    // partial O write (raw sums)
    {
        float* op = op_ws + (size_t)kh * NQROW * DIM + (bb + q0w) * DIM;
        #pragma unroll
        for (int dt = 0; dt < 8; ++dt)
            #pragma unroll
            for (int r = 0; r < 4; ++r)
                op[(size_t)(g * 4 + r) * DIM + dt * 16 + li] = accO[dt][r];
    }
}

// ============ ocomb: O = (Op0+Op1)*rinv ; write rinv ============
__global__ __launch_bounds__(256)
void ocomb(const float* __restrict__ op_ws,
           const float* __restrict__ rs_ws,
           float* __restrict__ og,
           float* __restrict__ ri_ws)
{
    __shared__ float rinvS[64];
    const int tid = threadIdx.x;
    const size_t R0 = (size_t)blockIdx.x * 64;

    if (tid < 64) {
        float s = rs_ws[R0 + tid] + rs_ws[(size_t)NQROW + R0 + tid];
        float inv = 1.0f / s;
        rinvS[tid] = inv;
        ri_ws[R0 + tid] = inv;
    }
    __syncthreads();

    const f32x4* p0 = reinterpret_cast<const f32x4*>(op_ws + R0 * DIM);
    const f32x4* p1 = reinterpret_cast<const f32x4*>(op_ws + (size_t)NQROW * DIM + R0 * DIM);
    f32x4* out = reinterpret_cast<f32x4*>(og + R0 * DIM);
    #pragma unroll
    for (int u = 0; u < 8; ++u) {
        const int i4 = u * 256 + tid;          // 2048 units
        const int row = i4 >> 5;
        f32x4 a = p0[i4];
        f32x4 c = p1[i4];
        const float inv = rinvS[row];
        a[0] = (a[0] + c[0]) * inv; a[1] = (a[1] + c[1]) * inv;
        a[2] = (a[2] + c[2]) * inv; a[3] = (a[3] + c[3]) * inv;
        __builtin_nontemporal_store(a, &out[i4]);
    }
}

// ============ wwrite: recompute QK^T, write W (barrier-free) ============
__global__ __launch_bounds__(256, 4)
void wwrite(const float* __restrict__ qg,
            const bf16x8* __restrict__ kf,
            const unsigned char* __restrict__ mb_ws,
            const float* __restrict__ ri_ws,
            float* __restrict__ wg)
{
    __shared__ __align__(16) float Wst[4][16][36];     // 9.2 KB

    const int tid  = threadIdx.x;
    const int wave = tid >> 6;
    const int lane = tid & 63;
    const int g    = lane >> 4;
    const int li   = lane & 15;

    const int wgid = blockIdx.x;           // 0..1023
    const int xcd  = wgid & 7;
    const int rest = wgid >> 3;
    const int b    = xcd + 8 * (rest & 1);
    const int r2   = rest >> 1;
    const int qb   = r2 >> 1;
    const int kh   = r2 & 1;
    const int q0w  = qb * 64 + wave * 16;
    const int qt16 = qb * 4 + wave;
    const int kb0  = kh * 32;

    const size_t bb = (size_t)b * LSEQ;

    const float qscale = 0.08838834764831845f * 1.4426950408889634f;
    bf16x8 qf[4];
    {
        const float* qrow = qg + (bb + q0w + li) * DIM + g * 8;
        #pragma unroll
        for (int d = 0; d < 4; ++d) {
            const float4* p4 = reinterpret_cast<const float4*>(qrow + d * 32);
            float4 x = p4[0];
            float4 y = p4[1];
            x.x *= qscale; x.y *= qscale; x.z *= qscale; x.w *= qscale;
            y.x *= qscale; y.y *= qscale; y.z *= qscale; y.w *= qscale;
            qf[d] = cvt8(x, y);
        }
    }

    float rinv[4];
    #pragma unroll
    for (int r = 0; r < 4; ++r) rinv[r] = ri_ws[bb + q0w + g * 4 + r];

    const bf16x8* KbL = kf + (size_t)b * NKBLK * 512 + lane;
    const unsigned char* mbp = mb_ws + (((size_t)b * 128 + qt16) * NKBLK) * 64 + lane;
    float* wrow = wg + (bb + q0w) * (size_t)LSEQ;

    auto w_iter = [&](int kblk, bf16x8* kc) {
        const unsigned byte = mbp[(size_t)kblk * 64];

        f32x4 s0 = (f32x4){0.f, 0.f, 0.f, 0.f};
        f32x4 s1 = (f32x4){0.f, 0.f, 0.f, 0.f};
        #pragma unroll
        for (int d = 0; d < 4; ++d) {
            s0 = __builtin_amdgcn_mfma_f32_16x16x32_bf16(qf[d], kc[d],     s0, 0, 0, 0);
            s1 = __builtin_amdgcn_mfma_f32_16x16x32_bf16(qf[d], kc[4 + d], s1, 0, 0, 0);
        }

        #pragma unroll
        for (int t2 = 0; t2 < 2; ++t2) {
            f32x4 sv = t2 ? s1 : s0;
            #pragma unroll
            for (int r = 0; r < 4; ++r) {
                float sc = ((byte >> (t2 * 4 + r)) & 1u) ? -1.0e9f : sv[r];
                Wst[wave][g * 4 + r][t2 * 16 + li] =
                    __builtin_amdgcn_exp2f(sc) * rinv[r];
            }
        }

        #pragma unroll
        for (int pp = 0; pp < 2; ++pp) {
            const int row = pp * 8 + (lane >> 3);
            const int col = (lane & 7) * 4;
            f32x4 wv = *reinterpret_cast<const f32x4*>(&Wst[wave][row][col]);
            __builtin_nontemporal_store(wv,
                reinterpret_cast<f32x4*>(wrow + (size_t)row * LSEQ + kblk * 32 + col));
        }
    };

    bf16x8 kA[8], kB[8];
    #pragma unroll
    for (int j = 0; j < 8; ++j) kA[j] = KbL[(size_t)kb0 * 512 + j * 64];
    for (int it = 0; it < 32; it += 2) {
        const int kblk = kb0 + it;
        #pragma unroll
        for (int j = 0; j < 8; ++j) kB[j] = KbL[(size_t)(kblk + 1) * 512 + j * 64];
        w_iter(kblk, kA);
        if (it + 2 < 32) {
            #pragma unroll
            for (int j = 0; j < 8; ++j) kA[j] = KbL[(size_t)(kblk + 2) * 512 + j * 64];
        }
        w_iter(kblk + 1, kB);
    }
}

// ========================= fallback (no workspace) =========================
__global__ __launch_bounds__(256, 2)
void sdpa_fused_plain(const float* __restrict__ qg,
                      const float* __restrict__ kg,
                      const float* __restrict__ vg,
                      const int*   __restrict__ maskg,
                      float* __restrict__ og,
                      float* __restrict__ wg)
{
    __shared__ __align__(16) __bf16 Es[16 * EPITCH];
    __shared__ float Osum[16 * DIM];
    __shared__ float rowpart[4][16];
    __shared__ float rowinv[16];

    const int tid  = threadIdx.x;
    const int wave = tid >> 6;
    const int lane = tid & 63;
    const int g    = lane >> 4;
    const int li   = lane & 15;
    const int qt = blockIdx.x;
    const int b  = blockIdx.y;
    const int q0 = qt * 16;

    for (int i = tid; i < 16 * DIM; i += 256) Osum[i] = 0.0f;

    const float qscale = 0.08838834764831845f * 1.4426950408889634f;
    bf16x8 qf[4];
    {
        const float* qrow = qg + ((size_t)b * LSEQ + q0 + li) * DIM + g * 8;
        #pragma unroll
        for (int d = 0; d < 4; ++d) {
            const float4* p4 = reinterpret_cast<const float4*>(qrow + d * 32);
            float4 x = p4[0];
            float4 y = p4[1];
            x.x *= qscale; x.y *= qscale; x.z *= qscale; x.w *= qscale;
            y.x *= qscale; y.y *= qscale; y.z *= qscale; y.w *= qscale;
            qf[d] = cvt8(x, y);
        }
    }

    float rsum[4] = {0.f, 0.f, 0.f, 0.f};
    f32x4 accO[8];
    #pragma unroll
    for (int i = 0; i < 8; ++i) accO[i] = (f32x4){0.f, 0.f, 0.f, 0.f};

    const int kwave0 = wave * 512;
    const size_t browbase = (size_t)b * LSEQ;

    for (int it = 0; it < 16; ++it) {
        const int kb = kwave0 + it * 32;
        f32x4 s0 = (f32x4){0.f, 0.f, 0.f, 0.f};
        f32x4 s1 = (f32x4){0.f, 0.f, 0.f, 0.f};
        {
            const float* kp0 = kg + (browbase + kb + li) * DIM + g * 8;
            const float* kp1 = kp0 + (size_t)16 * DIM;
            #pragma unroll
            for (int d = 0; d < 4; ++d) {
                const float4* a4 = reinterpret_cast<const float4*>(kp0 + d * 32);
                const float4* b4 = reinterpret_cast<const float4*>(kp1 + d * 32);
                s0 = __builtin_amdgcn_mfma_f32_16x16x32_bf16(qf[d], cvt8(a4[0], a4[1]), s0, 0, 0, 0);
                s1 = __builtin_amdgcn_mfma_f32_16x16x32_bf16(qf[d], cvt8(b4[0], b4[1]), s1, 0, 0, 0);
            }
        }
        const int* mbase = maskg + (browbase + q0) * LSEQ + kb + li;
        #pragma unroll
        for (int t = 0; t < 2; ++t) {
            f32x4 sv = t ? s1 : s0;
            const int col = kb + t * 16 + li;
            #pragma unroll
            for (int r = 0; r < 4; ++r) {
                const int m = mbase[(size_t)(g * 4 + r) * LSEQ + t * 16];
                float sc = m ? -1.0e9f : sv[r];
                float ev = __builtin_amdgcn_exp2f(sc);
                rsum[r] += ev;
                Es[(g * 4 + r) * EPITCH + col] = (__bf16)ev;
            }
        }
        bf16x8 af = *reinterpret_cast<const bf16x8*>(&Es[li * EPITCH + kb + g * 8]);
        const float* vb = vg + (browbase + kb + g * 8) * DIM + li;
        #pragma unroll
        for (int dt = 0; dt < 8; ++dt) {
            const float* vp = vb + dt * 16;
            bf16x8 bf;
            #pragma unroll
            for (int j = 0; j < 8; ++j) bf[j] = (__bf16)vp[(size_t)j * DIM];
            accO[dt] = __builtin_amdgcn_mfma_f32_16x16x32_bf16(af, bf, accO[dt], 0, 0, 0);
        }
    }

    #pragma unroll
    for (int off = 1; off < 16; off <<= 1) {
        #pragma unroll
        for (int r = 0; r < 4; ++r) rsum[r] += __shfl_xor(rsum[r], off, 64);
    }
    if (li == 0) {
        #pragma unroll
        for (int r = 0; r < 4; ++r) rowpart[wave][g * 4 + r] = rsum[r];
    }
    __syncthreads();
    #pragma unroll
    for (int dt = 0; dt < 8; ++dt) {
        #pragma unroll
        for (int r = 0; r < 4; ++r)
            atomicAdd(&Osum[(g * 4 + r) * DIM + dt * 16 + li], accO[dt][r]);
    }
    if (tid < 16) {
        float s = rowpart[0][tid] + rowpart[1][tid] + rowpart[2][tid] + rowpart[3][tid];
        rowinv[tid] = 1.0f / s;
    }
    __syncthreads();

    const size_t wbase = (browbase + q0) * LSEQ;
    for (int i = tid; i < 16 * (LSEQ / 8); i += 256) {
        const int row = i >> 8;
        const int col = (i & 255) * 8;
        bf16x8 e = *reinterpret_cast<const bf16x8*>(&Es[row * EPITCH + col]);
        const float inv = rowinv[row];
        float4 w0, w1;
        w0.x = (float)e[0] * inv; w0.y = (float)e[1] * inv;
        w0.z = (float)e[2] * inv; w0.w = (float)e[3] * inv;
        w1.x = (float)e[4] * inv; w1.y = (float)e[5] * inv;
        w1.z = (float)e[6] * inv; w1.w = (float)e[7] * inv;
        float* dst = wg + wbase + (size_t)row * LSEQ + col;
        *reinterpret_cast<float4*>(dst)     = w0;
        *reinterpret_cast<float4*>(dst + 4) = w1;
    }
    const size_t obase = (browbase + q0) * DIM;
    for (int i = tid; i < 16 * DIM; i += 256) {
        const int row = i >> 7;
        og[obase + i] = Osum[i] * rowinv[row];
    }
}

extern "C" void kernel_launch(void* const* d_in, const int* in_sizes, int n_in,
                              void* d_out, int out_size, void* d_ws, size_t ws_size,
                              hipStream_t stream) {
    const float* q    = (const float*)d_in[0];
    const float* k    = (const float*)d_in[1];
    const float* v    = (const float*)d_in[2];
    const int*   mask = (const int*)d_in[3];
    float* o = (float*)d_out;
    float* w = (float*)d_out + (size_t)BATCH * LSEQ * DIM;

    const size_t kfSize = (size_t)BATCH * NKBLK * 512 * 16;          // 8.39 MB
    const size_t vfSize = kfSize;                                    // 8.39 MB
    const size_t mbSize = (size_t)BATCH * 128 * NKBLK * 64;          // 8.39 MB
    const size_t opSize = (size_t)2 * NQROW * DIM * sizeof(float);   // 33.55 MB
    const size_t rsSize = (size_t)2 * NQROW * sizeof(float);         // 0.26 MB
    const size_t riSize = (size_t)NQROW * sizeof(float);             // 0.13 MB
    const size_t need   = kfSize + vfSize + mbSize + opSize + rsSize + riSize;

    if (ws_size >= need) {
        char* p = (char*)d_ws;
        bf16x8* kfp = (bf16x8*)p;                 p += kfSize;
        bf16x8* vfp = (bf16x8*)p;                 p += vfSize;
        unsigned char* mbp = (unsigned char*)p;   p += mbSize;
        float* opp = (float*)p;                   p += opSize;
        float* rsp = (float*)p;                   p += rsSize;
        float* rip = (float*)p;

        pack_k_kernel<<<dim3(NKBLK, BATCH), 256, 0, stream>>>(k, kfp);
        pack_v_kernel<<<dim3(NKBLK, BATCH), 256, 0, stream>>>(v, vfp);
        attn1<<<1024, 256, 0, stream>>>(q, kfp, vfp, mask, opp, rsp, mbp);
        ocomb<<<NQROW / 64, 256, 0, stream>>>(opp, rsp, o, rip);
        wwrite<<<1024, 256, 0, stream>>>(q, kfp, mbp, rip, w);
    } else {
        dim3 grid(LSEQ / 16, BATCH);
        sdpa_fused_plain<<<grid, 256, 0, stream>>>(q, k, v, mask, o, w);
    }
}